// Round 18
// baseline (126.211 us; speedup 1.0000x reference)
//
#include <hip/hip_runtime.h>
#include <math.h>

#define BATCH 16
#define NCLS 80
#define TOPK 100
#define NBOX 22743
#define NSLOT (NCLS*TOPK)   // 8000 per image
#define TPAD 22752          // padded (s,a)-major total per image
#define CAP 1024
#define NQ4 5688            // padded quads per image
#define NSEG 18
#define NZERO (BATCH*NCLS*256)   // ghist words

__device__ __forceinline__ float sigf(float x){ return 1.0f/(1.0f + expf(-x)); }
// fast sigmoid for binning only; rel err ~1e-6 << bin width (0.8%) => +-1 bin slack
__device__ __forceinline__ float fsigf(float x){
    return __builtin_amdgcn_rcpf(1.0f + __expf(-x));
}

#define BIN_OF(sc) ({ int _b = (int)(__float_as_uint(sc)>>16) - 0x3E99; _b < 0 ? 0 : (_b > 255 ? 255 : _b); })

// segment: one (scale,anchor[,chunk]) row slice; all fields block-uniform
struct Seg { const float* fbase; int a; int P; int qc; int confb; int nb; int lqoff; int tailq; };
__device__ __forceinline__ Seg segdec(int z, const float* f0, const float* f1, const float* f2){
    Seg s;
    if (z < 3){       s.a=z;   s.P=361;  s.qc=91;  s.confb=z*364;                s.nb=z;        s.fbase=f0; s.lqoff=0;      s.tailq=90; }
    else if (z < 6){  int a=z-3; s.a=a;  s.P=1444; s.qc=361; s.confb=1092+a*1444; s.nb=1083+a;  s.fbase=f1; s.lqoff=0;      s.tailq=-1; }
    else { int t=z-6; int a=t>>2, ch=t&3; s.a=a; s.P=5776; s.qc=361;
           s.confb=5424+a*5776+ch*1444;  s.nb=5415+a;  s.fbase=f2; s.lqoff=ch*361; s.tailq=-1; }
    return s;
}

// quad geometry: i in [0,5688) -> scale/anchor/pixel; conf_off == i*4
struct QGeo { int s; int a; int p; int P; int conf_off; int nb; bool tail; };
__device__ __forceinline__ QGeo qgeo(int i){
    QGeo g;
    if (i < 273){        g.s=0; g.a=i/91;   int lq=i-g.a*91;   g.P=361;  g.conf_off=g.a*364      + lq*4; g.nb=g.a;      g.p=lq*4; g.tail=(lq==90); }
    else if (i < 1356){  int l=i-273;  g.s=1; g.a=l/361;  int lq=l-g.a*361;  g.P=1444; g.conf_off=1092+g.a*1444+ lq*4; g.nb=1083+g.a; g.p=lq*4; g.tail=false; }
    else {               int l=i-1356; g.s=2; g.a=l/1444; int lq=l-g.a*1444; g.P=5776; g.conf_off=5424+g.a*5776+ lq*4; g.nb=5415+g.a; g.p=lq*4; g.tail=false; }
    return g;
}

// ------- LUT init: per-word geometry, shared by all (b,c) blocks -------------
__global__ __launch_bounds__(256)
void lutinit_kernel(uint2* __restrict__ lut)
{
    int w = blockIdx.x*256 + threadIdx.x;
    if (w >= NQ4) return;
    QGeo g = qgeo(w);
    int base0 = (g.a*85 + 5)*g.P + g.p;        // class-row offset within (b,s)
    int nb0   = g.nb + 3*g.p;                  // global box index of element 0
    lut[w] = make_uint2((unsigned)base0, (unsigned)nb0 | ((unsigned)g.s << 30));
}

// ------- decode (quad): boxes + conf (padded (s,a)-major); zeroes ghist ------
__global__ __launch_bounds__(256)
void decode_kernel(const float* __restrict__ f0, const float* __restrict__ f1,
                   const float* __restrict__ f2, const float* __restrict__ anchors,
                   const float* __restrict__ ishape,
                   float* __restrict__ boxes, float* __restrict__ conf2,
                   unsigned* __restrict__ gzero)
{
    int i = blockIdx.x*256 + threadIdx.x;
    int b = blockIdx.y;
    int tot = gridDim.x*gridDim.y*256;
    for (int g = (b*gridDim.x + blockIdx.x)*256 + threadIdx.x; g < NZERO; g += tot)
        gzero[g] = 0u;
    if (i >= NQ4) return;
    QGeo g = qgeo(i);
    const float* f = (g.s==0)?f0:((g.s==1)?f1:f2);
    int G = (g.s==0)?19:((g.s==1)?38:76);
    int abase = (g.s==0)?6:((g.s==1)?3:0);
    const float* fb = f + ((size_t)b*255 + g.a*85)*(size_t)g.P;
    // 5 row loads (tail quad spills <=3 floats into the NEXT channel row: in-bounds)
    float4 TX = *(const float4*)(fb + (size_t)0*g.P + g.p);
    float4 TY = *(const float4*)(fb + (size_t)1*g.P + g.p);
    float4 TW = *(const float4*)(fb + (size_t)2*g.P + g.p);
    float4 TH = *(const float4*)(fb + (size_t)3*g.P + g.p);
    float4 TC = *(const float4*)(fb + (size_t)4*g.P + g.p);
    const float* txp = (const float*)&TX; const float* typ = (const float*)&TY;
    const float* twp = (const float*)&TW; const float* thp = (const float*)&TH;
    const float* tcp = (const float*)&TC;

    float aw = anchors[(abase+g.a)*2+0];
    float ah = anchors[(abase+g.a)*2+1];
    float ih = ishape[0], iw = ishape[1];
    float mm = fminf(608.0f/ih, 608.0f/iw);
    float nh = rintf(ih*mm), nw = rintf(iw*mm);
    float offy = (608.0f - nh) / 2.0f / 608.0f;
    float offx = (608.0f - nw) / 2.0f / 608.0f;
    float scy = 608.0f/nh, scx = 608.0f/nw;
    float gg = (float)G;
    int valid = g.tail ? 1 : 4;
    float cfout[4] = {0.f, 0.f, 0.f, 0.f};
#pragma unroll
    for (int j=0; j<4; j++){
        if (j < valid){
            int px = g.p + j;
            int yy = px / G, xx = px - yy*G;
            float xn = (sigf(txp[j]) + (float)xx) / gg;
            float yn = (sigf(typ[j]) + (float)yy) / gg;
            float wn = aw * expf(twp[j]) / 608.0f;
            float hn = ah * expf(thp[j]) / 608.0f;
            float y = (yn - offy)*scy;
            float x = (xn - offx)*scx;
            float hh = hn*scy, ww = wn*scx;
            int n = g.nb + 3*px;
            float4 bx;
            bx.x = (y - hh/2.0f)*ih;
            bx.y = (x - ww/2.0f)*iw;
            bx.z = (y + hh/2.0f)*ih;
            bx.w = (x + ww/2.0f)*iw;
            *(float4*)&boxes[((size_t)b*NBOX + n)*4] = bx;
            cfout[j] = sigf(tcp[j]);
        }
    }
    float4 cv; cv.x=cfout[0]; cv.y=cfout[1]; cv.z=cfout[2]; cv.w=cfout[3];
    *(float4*)&conf2[(size_t)b*TPAD + g.conf_off] = cv;
}

// ------- scan pass (r10-proven): APPROX histogram (+byte-bin cache) ----------
template<bool WRITEB>
__global__ __launch_bounds__(256)
void scan_kernel(const float* __restrict__ f0, const float* __restrict__ f1,
                 const float* __restrict__ f2, const float* __restrict__ conf2,
                 unsigned int* __restrict__ ghist, unsigned char* __restrict__ binb)
{
    int cg = blockIdx.x, b = blockIdx.y, z = blockIdx.z, tid = threadIdx.x;
    int c0 = cg*4;
    int bc0 = b*NCLS + c0;
    __shared__ unsigned int h[4][256];
    h[0][tid]=0; h[1][tid]=0; h[2][tid]=0; h[3][tid]=0;
    __syncthreads();
    Seg sg = segdec(z, f0, f1, f2);
    const int P = sg.P, qc = sg.qc;
    const float* cfp = conf2 + (size_t)b*TPAD + sg.confb;
    const float* prb = sg.fbase + ((size_t)b*255 + sg.a*85 + 5 + c0)*(size_t)P + sg.lqoff*4;

    int lqA = tid, lqB = tid + 256;
    bool vA = lqA < qc, vB = lqB < qc;
    float4 cfA, cfB, A0, A1, A2, A3, B0, B1, B2, B3;
    if (vA){
        const float* pA = prb + lqA*4;
        cfA = *(const float4*)(cfp + lqA*4);
        A0 = *(const float4*)pA;         A1 = *(const float4*)(pA + P);
        A2 = *(const float4*)(pA + 2*P); A3 = *(const float4*)(pA + 3*P);
    }
    if (vB){
        const float* pB = prb + lqB*4;
        cfB = *(const float4*)(cfp + lqB*4);
        B0 = *(const float4*)pB;         B1 = *(const float4*)(pB + P);
        B2 = *(const float4*)(pB + 2*P); B3 = *(const float4*)(pB + 3*P);
    }
#define HQUAD(cls, Q, CF, LQ) { \
    float s0 = CF.x*fsigf(Q.x), s1 = CF.y*fsigf(Q.y), s2 = CF.z*fsigf(Q.z), s3 = CF.w*fsigf(Q.w); \
    int b0 = BIN_OF(s0), b1 = BIN_OF(s1), b2 = BIN_OF(s2), b3 = BIN_OF(s3); \
    bool k0 = s0 > 0.2995f, k1 = s1 > 0.2995f, k2 = s2 > 0.2995f, k3 = s3 > 0.2995f; \
    if (k0) atomicAdd(&h[cls][b0], 1u); \
    if (k1) atomicAdd(&h[cls][b1], 1u); \
    if (k2) atomicAdd(&h[cls][b2], 1u); \
    if (k3) atomicAdd(&h[cls][b3], 1u); \
    if (WRITEB){ \
        unsigned ub = (k0 ? (unsigned)(b0+1) : 0u) | ((k1 ? (unsigned)(b1+1) : 0u)<<8) \
                    | ((k2 ? (unsigned)(b2+1) : 0u)<<16) | ((k3 ? (unsigned)(b3+1) : 0u)<<24); \
        *(unsigned*)(binb + (size_t)(bc0+cls)*TPAD + sg.confb + (LQ)*4) = ub; } }
    if (vA){
        if (lqA == sg.tailq){
            A0.y=A0.z=A0.w=-INFINITY; A1.y=A1.z=A1.w=-INFINITY;
            A2.y=A2.z=A2.w=-INFINITY; A3.y=A3.z=A3.w=-INFINITY;
        }
        HQUAD(0, A0, cfA, lqA) HQUAD(1, A1, cfA, lqA) HQUAD(2, A2, cfA, lqA) HQUAD(3, A3, cfA, lqA)
    }
    if (vB){
        HQUAD(0, B0, cfB, lqB) HQUAD(1, B1, cfB, lqB) HQUAD(2, B2, cfB, lqB) HQUAD(3, B3, cfB, lqB)
    }
#undef HQUAD
    __syncthreads();
    size_t hb = ((size_t)bc0)*256 + tid;
    if (h[0][tid]) atomicAdd(&ghist[hb      ], h[0][tid]);
    if (h[1][tid]) atomicAdd(&ghist[hb + 256], h[1][tid]);
    if (h[2][tid]) atomicAdd(&ghist[hb + 512], h[2][tid]);
    if (h[3][tid]) atomicAdd(&ghist[hb + 768], h[3][tid]);
}

// ------- selnms per (b,c): ghist row -> Tb; flat uint4 binb sweep with
//         geometry LUT; exact rescore; bitonic; matrix NMS; write out --------
template<bool WITHB>
__global__ __launch_bounds__(256)
void selnms_kernel(const float* __restrict__ f0, const float* __restrict__ f1,
                   const float* __restrict__ f2, const float* __restrict__ conf2,
                   const unsigned char* __restrict__ binb,
                   const uint2* __restrict__ lut,
                   const unsigned int* __restrict__ ghist,
                   const float* __restrict__ boxes, float* __restrict__ out)
{
    int c = blockIdx.x, b = blockIdx.y, tid = threadIdx.x;
    int bc = b*NCLS + c;
    __shared__ int sufA[256], sufB[256];
    __shared__ float cs[CAP];
    __shared__ int   ci[CAP];
    __shared__ float by1[TOPK], bx1[TOPK], by2[TOPK], bx2[TOPK], bar_[TOPK];
    __shared__ unsigned sup[TOPK][4];
    __shared__ unsigned keepw[4];
    __shared__ const float* baseS[3];
    __shared__ int cnt, TbS;
    if (tid == 0){ cnt = 0; TbS = 0; }
    if (tid < 4) keepw[tid] = 0u;
    if (tid < 3){
        int Ps = (tid==0)?361:((tid==1)?1444:5776);
        const float* fb = (tid==0)?f0:((tid==1)?f1:f2);
        baseS[tid] = fb + (size_t)b*255*(size_t)Ps + (size_t)c*(size_t)Ps;
    }
    for (int r=tid; r<TOPK; r+=256){ sup[r][0]=0u; sup[r][1]=0u; sup[r][2]=0u; sup[r][3]=0u; }
    sufA[tid] = (int)ghist[(size_t)bc*256 + tid];
    __syncthreads();
    int* cur = sufA; int* nxt = sufB;
    for (int d=1; d<256; d<<=1){
        int v = cur[tid] + ((tid+d) < 256 ? cur[tid+d] : 0);
        nxt[tid] = v;
        __syncthreads();
        int* t_ = cur; cur = nxt; nxt = t_;
    }
    if (cur[tid] >= TOPK && (tid == 255 || cur[tid+1] < TOPK)) TbS = tid;
    __syncthreads();
    int gate = TbS - 2; if (gate < 0) gate = 0;   // slack covers +-1 approx-bin error

    if (WITHB){
        const uint4* bw = (const uint4*)(binb + (size_t)bc*TPAD);
        const float* cfb = conf2 + (size_t)b*TPAD;
        for (int i = tid; i < NQ4/4; i += 256){
            uint4 u4 = bw[i];
            if (!(u4.x | u4.y | u4.z | u4.w)) continue;
            unsigned wv[4] = {u4.x, u4.y, u4.z, u4.w};
#pragma unroll
            for (int k=0; k<4; k++){
                unsigned ub = wv[k];
                if (!ub) continue;
                int w = i*4 + k;
                uint2 L = lut[w];
                int base0 = (int)L.x;
                int nb0   = (int)(L.y & 0x3FFFFFFFu);
                int s     = (int)(L.y >> 30);
                const float* pb = baseS[s] + base0;
#pragma unroll
                for (int j=0; j<4; j++){
                    unsigned bj = (ub >> (8*j)) & 0xFFu;
                    if (bj && (int)bj - 1 >= gate){
                        float cf = cfb[w*4 + j];
                        float pv = pb[j];
                        float sc = cf * sigf(pv);      // exact score, bit-identical
                        int pos = atomicAdd(&cnt, 1);
                        if (pos < CAP){ cs[pos] = sc; ci[pos] = nb0 + 3*j; }
                    }
                }
            }
        }
    } else {
        for (int i = tid; i < NQ4; i += 256){
            QGeo g = qgeo(i);
            const float* f = (g.s==0)?f0:((g.s==1)?f1:f2);
            float4 cf4 = *(const float4*)(conf2 + (size_t)b*TPAD + g.conf_off);
            const float* pr = f + ((size_t)b*255 + g.a*85 + 5 + c)*(size_t)g.P + g.p;
            float pv[4];
            if (!g.tail){
                float4 t = *(const float4*)pr;
                pv[0]=t.x; pv[1]=t.y; pv[2]=t.z; pv[3]=t.w;
            } else {
                pv[0] = pr[0]; pv[1] = -INFINITY; pv[2] = -INFINITY; pv[3] = -INFINITY;
            }
            const float* cfp = (const float*)&cf4;
#pragma unroll
            for (int j=0; j<4; j++){
                float st = cfp[j]*fsigf(pv[j]);
                if (st > 0.2995f && BIN_OF(st) >= gate){
                    float sc = cfp[j]*sigf(pv[j]);
                    int pos = atomicAdd(&cnt, 1);
                    if (pos < CAP){ cs[pos] = sc; ci[pos] = g.nb + 3*(g.p + j); }
                }
            }
        }
    }
    __syncthreads();
    int n = cnt; if (n > CAP) n = CAP;

    // bitonic sort: score desc, idx asc
    int S = 128; while (S < n) S <<= 1;
    for (int t=tid; t<S; t+=256){
        if (t >= n){ cs[t] = -INFINITY; ci[t] = 0x7FFFFFFF; }
    }
    __syncthreads();
    for (int k=2; k<=S; k<<=1){
        for (int j=k>>1; j>0; j>>=1){
            for (int t=tid; t<S; t+=256){
                int ixj = t ^ j;
                if (ixj > t){
                    float s1 = cs[t], s2 = cs[ixj];
                    int   i1 = ci[t], i2 = ci[ixj];
                    bool b2_first = (s2 > s1) || (s2 == s1 && i2 < i1);
                    bool b1_first = (s1 > s2) || (s1 == s2 && i1 < i2);
                    bool desc = ((t & k) == 0);
                    bool sw = desc ? b2_first : b1_first;
                    if (sw){ cs[t]=s2; cs[ixj]=s1; ci[t]=i2; ci[ixj]=i1; }
                }
            }
            __syncthreads();
        }
    }

    // load top-100 boxes; set valid bits
    if (tid < TOPK){
        float s = cs[tid];
        float y1=0.f,x1=0.f,y2=0.f,x2=0.f;
        if (s > 0.3f){
            size_t q = ((size_t)b*NBOX + ci[tid])*4;
            y1=boxes[q]; x1=boxes[q+1]; y2=boxes[q+2]; x2=boxes[q+3];
            atomicOr(&keepw[tid>>5], 1u << (tid & 31));
        }
        by1[tid]=y1; bx1[tid]=x1; by2[tid]=y2; bx2[tid]=x2;
        bar_[tid] = (y2-y1)*(x2-x1);
    }
    __syncthreads();

    // all-pairs IoU -> suppression masks (bit j of sup[i] iff j>i and iou>0.3)
    for (int p = tid; p < TOPK*TOPK; p += 256){
        int i = p / TOPK, j = p - i*TOPK;
        if (j > i){
            float q1 = fmaxf(by1[i], by1[j]);
            float q2 = fmaxf(bx1[i], bx1[j]);
            float q3 = fminf(by2[i], by2[j]);
            float q4 = fminf(bx2[i], bx2[j]);
            float inter = fmaxf(q3-q1, 0.0f)*fmaxf(q4-q2, 0.0f);
            float iou = inter/(bar_[i] + bar_[j] - inter + 1e-9f);
            if (iou > 0.3f) atomicOr(&sup[i][j>>5], 1u << (j & 31));
        }
    }
    __syncthreads();

    // serial greedy on one thread: keep &= ~sup[i] for each surviving i
    if (tid == 0){
        unsigned k0 = keepw[0], k1 = keepw[1], k2 = keepw[2], k3 = keepw[3];
        for (int i = 0; i < TOPK; i++){
            uint4 sp = *(const uint4*)sup[i];
            unsigned kw = (i < 32) ? k0 : ((i < 64) ? k1 : ((i < 96) ? k2 : k3));
            if (kw & (1u << (i & 31))){
                k0 &= ~sp.x; k1 &= ~sp.y; k2 &= ~sp.z; k3 &= ~sp.w;
            }
        }
        keepw[0]=k0; keepw[1]=k1; keepw[2]=k2; keepw[3]=k3;
    }
    __syncthreads();

    if (tid < TOPK){
        bool kept = (keepw[tid>>5] >> (tid & 31)) & 1u;
        size_t o5 = ((size_t)(bc*TOPK + tid))*5;
        out[o5+0] = kept ? by1[tid] : 0.f;
        out[o5+1] = kept ? bx1[tid] : 0.f;
        out[o5+2] = kept ? by2[tid] : 0.f;
        out[o5+3] = kept ? bx2[tid] : 0.f;
        out[o5+4] = kept ? cs[tid]  : 0.f;
    }
}

// -------- per-image top-50 cap via histogram select --------
__global__ __launch_bounds__(1024)
void cap_kernel(float* __restrict__ out)
{
    int b = blockIdx.x, tid = threadIdx.x;
    __shared__ unsigned int h[256];
    __shared__ int sufA[256], sufB[256];
    __shared__ float cs[512];
    __shared__ int   ci[512];
    __shared__ int cnt, T50;
    __shared__ unsigned char msk[NSLOT];
    if (tid < 256) h[tid] = 0;
    if (tid == 0){ cnt = 0; T50 = 0; }
    for (int u=tid; u<NSLOT; u+=1024) msk[u] = 0;
    __syncthreads();

    for (int u=tid; u<NSLOT; u+=1024){
        float v = out[((size_t)b*NSLOT + u)*5 + 4];
        if (v > 0.0f) atomicAdd(&h[BIN_OF(v)], 1u);
    }
    __syncthreads();

    if (tid < 256) sufA[tid] = (int)h[tid];
    __syncthreads();
    int* cur = sufA; int* nxt = sufB;
    for (int d=1; d<256; d<<=1){
        if (tid < 256) nxt[tid] = cur[tid] + ((tid+d) < 256 ? cur[tid+d] : 0);
        __syncthreads();
        int* t_ = cur; cur = nxt; nxt = t_;
    }
    if (tid < 256){
        if (cur[tid] >= 50 && (tid == 255 || cur[tid+1] < 50)) T50 = tid;
    }
    __syncthreads();
    int T = T50;

    for (int u=tid; u<NSLOT; u+=1024){
        float v = out[((size_t)b*NSLOT + u)*5 + 4];
        if (v > 0.0f && BIN_OF(v) >= T){
            int pos = atomicAdd(&cnt, 1);
            if (pos < 512){ cs[pos] = v; ci[pos] = u; }
        }
    }
    __syncthreads();
    int n = cnt; if (n > 512) n = 512;
    for (int t=tid; t<512; t+=1024){
        if (t >= n){ cs[t] = -INFINITY; ci[t] = 0x7FFFFFFF; }
    }
    __syncthreads();

    int S = 64; while (S < n) S <<= 1;
    for (int k=2; k<=S; k<<=1){
        for (int j=k>>1; j>0; j>>=1){
            for (int t=tid; t<S; t+=1024){
                int ixj = t ^ j;
                if (ixj > t){
                    float s1 = cs[t], s2 = cs[ixj];
                    int   i1 = ci[t], i2 = ci[ixj];
                    bool b2_first = (s2 > s1) || (s2 == s1 && i2 < i1);
                    bool b1_first = (s1 > s2) || (s1 == s2 && i1 < i2);
                    bool desc = ((t & k) == 0);
                    bool sw = desc ? b2_first : b1_first;
                    if (sw){ cs[t]=s2; cs[ixj]=s1; ci[t]=i2; ci[ixj]=i1; }
                }
            }
            __syncthreads();
        }
    }

    if (tid < 50 && tid < n) msk[ci[tid]] = 1;
    __syncthreads();

    for (int u=tid; u<NSLOT; u+=1024){
        size_t o5 = ((size_t)b*NSLOT + u)*5;
        float v = out[o5 + 4];
        if (v > 0.0f && !msk[u]){
            out[o5+0]=0.f; out[o5+1]=0.f; out[o5+2]=0.f; out[o5+3]=0.f; out[o5+4]=0.f;
        }
    }
}

extern "C" void kernel_launch(void* const* d_in, const int* in_sizes, int n_in,
                              void* d_out, int out_size, void* d_ws, size_t ws_size,
                              hipStream_t stream)
{
    const float* f0 = (const float*)d_in[0];
    const float* f1 = (const float*)d_in[1];
    const float* f2 = (const float*)d_in[2];
    const float* anchors = (const float*)d_in[3];
    const float* ishape  = (const float*)d_in[4];
    float* out = (float*)d_out;

    float* boxes = (float*)d_ws;                                   // 16*22743*4
    float* conf2 = boxes + (size_t)BATCH*NBOX*4;                   // 16*22752
    unsigned* ghist = (unsigned*)(conf2 + (size_t)BATCH*TPAD);     // 1280*256
    uint2* lut = (uint2*)(ghist + (size_t)NZERO);                  // 5688*8 B
    unsigned char* binb = (unsigned char*)(lut + NQ4);             // 16*80*22752 B

    size_t words = (size_t)BATCH*NBOX*4 + (size_t)BATCH*TPAD + (size_t)NZERO + 2*(size_t)NQ4;
    size_t need = words*4 + (size_t)BATCH*NCLS*TPAD;
    bool useB = ws_size >= need;

    lutinit_kernel<<<(NQ4 + 255)/256, 256, 0, stream>>>(lut);

    dim3 dgrid((NQ4 + 255)/256, BATCH);
    decode_kernel<<<dgrid, 256, 0, stream>>>(f0, f1, f2, anchors, ishape,
                                             boxes, conf2, ghist);

    dim3 hgrid(NCLS/4, BATCH, NSEG);
    if (useB)
        scan_kernel<true><<<hgrid, 256, 0, stream>>>(f0, f1, f2, conf2, ghist, binb);
    else
        scan_kernel<false><<<hgrid, 256, 0, stream>>>(f0, f1, f2, conf2, ghist, binb);

    dim3 sgrid(NCLS, BATCH);
    if (useB)
        selnms_kernel<true><<<sgrid, 256, 0, stream>>>(f0, f1, f2, conf2, binb, lut,
                                                       ghist, boxes, out);
    else
        selnms_kernel<false><<<sgrid, 256, 0, stream>>>(f0, f1, f2, conf2, binb, lut,
                                                        ghist, boxes, out);

    cap_kernel<<<BATCH, 1024, 0, stream>>>(out);
}

// Round 19
// 114.512 us; speedup vs baseline: 1.1022x; 1.1022x over previous
//
#include <hip/hip_runtime.h>
#include <math.h>

#define BATCH 16
#define NCLS 80
#define TOPK 100
#define NBOX 22743
#define NSLOT (NCLS*TOPK)   // 8000 per image
#define TPAD 22752          // padded (s,a)-major total per image
#define CAP 1024
#define NQ4 5688            // padded quads per image
#define NSEG 18
#define NZERO (BATCH*NCLS*256)   // ghist words

__device__ __forceinline__ float sigf(float x){ return 1.0f/(1.0f + expf(-x)); }
// fast sigmoid for binning only; rel err ~1e-6 << bin width (0.8%) => +-1 bin slack
__device__ __forceinline__ float fsigf(float x){
    return __builtin_amdgcn_rcpf(1.0f + __expf(-x));
}

#define BIN_OF(sc) ({ int _b = (int)(__float_as_uint(sc)>>16) - 0x3E99; _b < 0 ? 0 : (_b > 255 ? 255 : _b); })

// segment: one (scale,anchor[,chunk]) row slice; all fields block-uniform
struct Seg { const float* fbase; int a; int P; int qc; int confb; int nb; int lqoff; int tailq; };
__device__ __forceinline__ Seg segdec(int z, const float* f0, const float* f1, const float* f2){
    Seg s;
    if (z < 3){       s.a=z;   s.P=361;  s.qc=91;  s.confb=z*364;                s.nb=z;        s.fbase=f0; s.lqoff=0;      s.tailq=90; }
    else if (z < 6){  int a=z-3; s.a=a;  s.P=1444; s.qc=361; s.confb=1092+a*1444; s.nb=1083+a;  s.fbase=f1; s.lqoff=0;      s.tailq=-1; }
    else { int t=z-6; int a=t>>2, ch=t&3; s.a=a; s.P=5776; s.qc=361;
           s.confb=5424+a*5776+ch*1444;  s.nb=5415+a;  s.fbase=f2; s.lqoff=ch*361; s.tailq=-1; }
    return s;
}

// quad geometry: i in [0,5688) -> scale/anchor/pixel; conf_off == i*4
struct QGeo { int s; int a; int p; int P; int conf_off; int nb; bool tail; };
__device__ __forceinline__ QGeo qgeo(int i){
    QGeo g;
    if (i < 273){        g.s=0; g.a=i/91;   int lq=i-g.a*91;   g.P=361;  g.conf_off=g.a*364      + lq*4; g.nb=g.a;      g.p=lq*4; g.tail=(lq==90); }
    else if (i < 1356){  int l=i-273;  g.s=1; g.a=l/361;  int lq=l-g.a*361;  g.P=1444; g.conf_off=1092+g.a*1444+ lq*4; g.nb=1083+g.a; g.p=lq*4; g.tail=false; }
    else {               int l=i-1356; g.s=2; g.a=l/1444; int lq=l-g.a*1444; g.P=5776; g.conf_off=5424+g.a*5776+ lq*4; g.nb=5415+g.a; g.p=lq*4; g.tail=false; }
    return g;
}

// ------- decode (quad): boxes + conf (padded (s,a)-major); zeroes ghist ------
__global__ __launch_bounds__(256)
void decode_kernel(const float* __restrict__ f0, const float* __restrict__ f1,
                   const float* __restrict__ f2, const float* __restrict__ anchors,
                   const float* __restrict__ ishape,
                   float* __restrict__ boxes, float* __restrict__ conf2,
                   unsigned* __restrict__ gzero)
{
    int i = blockIdx.x*256 + threadIdx.x;
    int b = blockIdx.y;
    int tot = gridDim.x*gridDim.y*256;
    for (int g = (b*gridDim.x + blockIdx.x)*256 + threadIdx.x; g < NZERO; g += tot)
        gzero[g] = 0u;
    if (i >= NQ4) return;
    QGeo g = qgeo(i);
    const float* f = (g.s==0)?f0:((g.s==1)?f1:f2);
    int G = (g.s==0)?19:((g.s==1)?38:76);
    int abase = (g.s==0)?6:((g.s==1)?3:0);
    const float* fb = f + ((size_t)b*255 + g.a*85)*(size_t)g.P;
    // 5 row loads (tail quad spills <=3 floats into the NEXT channel row: in-bounds)
    float4 TX = *(const float4*)(fb + (size_t)0*g.P + g.p);
    float4 TY = *(const float4*)(fb + (size_t)1*g.P + g.p);
    float4 TW = *(const float4*)(fb + (size_t)2*g.P + g.p);
    float4 TH = *(const float4*)(fb + (size_t)3*g.P + g.p);
    float4 TC = *(const float4*)(fb + (size_t)4*g.P + g.p);
    const float* txp = (const float*)&TX; const float* typ = (const float*)&TY;
    const float* twp = (const float*)&TW; const float* thp = (const float*)&TH;
    const float* tcp = (const float*)&TC;

    float aw = anchors[(abase+g.a)*2+0];
    float ah = anchors[(abase+g.a)*2+1];
    float ih = ishape[0], iw = ishape[1];
    float mm = fminf(608.0f/ih, 608.0f/iw);
    float nh = rintf(ih*mm), nw = rintf(iw*mm);
    float offy = (608.0f - nh) / 2.0f / 608.0f;
    float offx = (608.0f - nw) / 2.0f / 608.0f;
    float scy = 608.0f/nh, scx = 608.0f/nw;
    float gg = (float)G;
    int valid = g.tail ? 1 : 4;
    float cfout[4] = {0.f, 0.f, 0.f, 0.f};
#pragma unroll
    for (int j=0; j<4; j++){
        if (j < valid){
            int px = g.p + j;
            int yy = px / G, xx = px - yy*G;
            float xn = (sigf(txp[j]) + (float)xx) / gg;
            float yn = (sigf(typ[j]) + (float)yy) / gg;
            float wn = aw * expf(twp[j]) / 608.0f;
            float hn = ah * expf(thp[j]) / 608.0f;
            float y = (yn - offy)*scy;
            float x = (xn - offx)*scx;
            float hh = hn*scy, ww = wn*scx;
            int n = g.nb + 3*px;
            float4 bx;
            bx.x = (y - hh/2.0f)*ih;
            bx.y = (x - ww/2.0f)*iw;
            bx.z = (y + hh/2.0f)*ih;
            bx.w = (x + ww/2.0f)*iw;
            *(float4*)&boxes[((size_t)b*NBOX + n)*4] = bx;
            cfout[j] = sigf(tcp[j]);
        }
    }
    float4 cv; cv.x=cfout[0]; cv.y=cfout[1]; cv.z=cfout[2]; cv.w=cfout[3];
    *(float4*)&conf2[(size_t)b*TPAD + g.conf_off] = cv;
}

// ------- scan pass (r10-proven): APPROX histogram (+byte-bin cache) ----------
template<bool WRITEB>
__global__ __launch_bounds__(256)
void scan_kernel(const float* __restrict__ f0, const float* __restrict__ f1,
                 const float* __restrict__ f2, const float* __restrict__ conf2,
                 unsigned int* __restrict__ ghist, unsigned char* __restrict__ binb)
{
    int cg = blockIdx.x, b = blockIdx.y, z = blockIdx.z, tid = threadIdx.x;
    int c0 = cg*4;
    int bc0 = b*NCLS + c0;
    __shared__ unsigned int h[4][256];
    h[0][tid]=0; h[1][tid]=0; h[2][tid]=0; h[3][tid]=0;
    __syncthreads();
    Seg sg = segdec(z, f0, f1, f2);
    const int P = sg.P, qc = sg.qc;
    const float* cfp = conf2 + (size_t)b*TPAD + sg.confb;
    const float* prb = sg.fbase + ((size_t)b*255 + sg.a*85 + 5 + c0)*(size_t)P + sg.lqoff*4;

    int lqA = tid, lqB = tid + 256;
    bool vA = lqA < qc, vB = lqB < qc;
    float4 cfA, cfB, A0, A1, A2, A3, B0, B1, B2, B3;
    if (vA){
        const float* pA = prb + lqA*4;
        cfA = *(const float4*)(cfp + lqA*4);
        A0 = *(const float4*)pA;         A1 = *(const float4*)(pA + P);
        A2 = *(const float4*)(pA + 2*P); A3 = *(const float4*)(pA + 3*P);
    }
    if (vB){
        const float* pB = prb + lqB*4;
        cfB = *(const float4*)(cfp + lqB*4);
        B0 = *(const float4*)pB;         B1 = *(const float4*)(pB + P);
        B2 = *(const float4*)(pB + 2*P); B3 = *(const float4*)(pB + 3*P);
    }
#define HQUAD(cls, Q, CF, LQ) { \
    float s0 = CF.x*fsigf(Q.x), s1 = CF.y*fsigf(Q.y), s2 = CF.z*fsigf(Q.z), s3 = CF.w*fsigf(Q.w); \
    int b0 = BIN_OF(s0), b1 = BIN_OF(s1), b2 = BIN_OF(s2), b3 = BIN_OF(s3); \
    bool k0 = s0 > 0.2995f, k1 = s1 > 0.2995f, k2 = s2 > 0.2995f, k3 = s3 > 0.2995f; \
    if (k0) atomicAdd(&h[cls][b0], 1u); \
    if (k1) atomicAdd(&h[cls][b1], 1u); \
    if (k2) atomicAdd(&h[cls][b2], 1u); \
    if (k3) atomicAdd(&h[cls][b3], 1u); \
    if (WRITEB){ \
        unsigned ub = (k0 ? (unsigned)(b0+1) : 0u) | ((k1 ? (unsigned)(b1+1) : 0u)<<8) \
                    | ((k2 ? (unsigned)(b2+1) : 0u)<<16) | ((k3 ? (unsigned)(b3+1) : 0u)<<24); \
        *(unsigned*)(binb + (size_t)(bc0+cls)*TPAD + sg.confb + (LQ)*4) = ub; } }
    if (vA){
        if (lqA == sg.tailq){
            A0.y=A0.z=A0.w=-INFINITY; A1.y=A1.z=A1.w=-INFINITY;
            A2.y=A2.z=A2.w=-INFINITY; A3.y=A3.z=A3.w=-INFINITY;
        }
        HQUAD(0, A0, cfA, lqA) HQUAD(1, A1, cfA, lqA) HQUAD(2, A2, cfA, lqA) HQUAD(3, A3, cfA, lqA)
    }
    if (vB){
        HQUAD(0, B0, cfB, lqB) HQUAD(1, B1, cfB, lqB) HQUAD(2, B2, cfB, lqB) HQUAD(3, B3, cfB, lqB)
    }
#undef HQUAD
    __syncthreads();
    size_t hb = ((size_t)bc0)*256 + tid;
    if (h[0][tid]) atomicAdd(&ghist[hb      ], h[0][tid]);
    if (h[1][tid]) atomicAdd(&ghist[hb + 256], h[1][tid]);
    if (h[2][tid]) atomicAdd(&ghist[hb + 512], h[2][tid]);
    if (h[3][tid]) atomicAdd(&ghist[hb + 768], h[3][tid]);
}

// ------- selnms per (b,c): ghist row -> Tb; flat uint4 binb sweep; exact
//         rescore; bitonic sort; parallel-IoU-matrix NMS; write out ----------
template<bool WITHB>
__global__ __launch_bounds__(256)
void selnms_kernel(const float* __restrict__ f0, const float* __restrict__ f1,
                   const float* __restrict__ f2, const float* __restrict__ conf2,
                   const unsigned char* __restrict__ binb,
                   const unsigned int* __restrict__ ghist,
                   const float* __restrict__ boxes, float* __restrict__ out)
{
    int c = blockIdx.x, b = blockIdx.y, tid = threadIdx.x;
    int bc = b*NCLS + c;
    __shared__ int sufA[256], sufB[256];
    __shared__ float cs[CAP];
    __shared__ int   ci[CAP];
    __shared__ float by1[TOPK], bx1[TOPK], by2[TOPK], bx2[TOPK], bar_[TOPK];
    __shared__ unsigned sup[TOPK][4];
    __shared__ unsigned keepw[4];
    __shared__ int cnt, TbS;
    if (tid == 0){ cnt = 0; TbS = 0; }
    if (tid < 4) keepw[tid] = 0u;
    for (int r=tid; r<TOPK; r+=256){ sup[r][0]=0u; sup[r][1]=0u; sup[r][2]=0u; sup[r][3]=0u; }
    sufA[tid] = (int)ghist[(size_t)bc*256 + tid];
    __syncthreads();
    int* cur = sufA; int* nxt = sufB;
    for (int d=1; d<256; d<<=1){
        int v = cur[tid] + ((tid+d) < 256 ? cur[tid+d] : 0);
        nxt[tid] = v;
        __syncthreads();
        int* t_ = cur; cur = nxt; nxt = t_;
    }
    if (cur[tid] >= TOPK && (tid == 255 || cur[tid+1] < TOPK)) TbS = tid;
    __syncthreads();
    int gate = TbS - 2; if (gate < 0) gate = 0;   // slack covers +-1 approx-bin error

    if (WITHB){
        const uint4* bw = (const uint4*)(binb + (size_t)bc*TPAD);
        for (int i = tid; i < NQ4/4; i += 256){
            uint4 u4 = bw[i];
            unsigned wv[4] = {u4.x, u4.y, u4.z, u4.w};
#pragma unroll
            for (int k=0; k<4; k++){
                unsigned ub = wv[k];
                if (!ub) continue;
                int w = i*4 + k;
                QGeo g = qgeo(w);
                const float* f = (g.s==0)?f0:((g.s==1)?f1:f2);
                const float* pr = f + ((size_t)b*255 + g.a*85 + 5 + c)*(size_t)g.P + g.p;
#pragma unroll
                for (int j=0; j<4; j++){
                    unsigned bj = (ub >> (8*j)) & 0xFFu;
                    if (bj && (int)bj - 1 >= gate){
                        float cf = conf2[(size_t)b*TPAD + w*4 + j];
                        float pv = pr[j];
                        float sc = cf * sigf(pv);      // exact score, bit-identical
                        int pos = atomicAdd(&cnt, 1);
                        if (pos < CAP){ cs[pos] = sc; ci[pos] = g.nb + 3*(g.p + j); }
                    }
                }
            }
        }
    } else {
        for (int i = tid; i < NQ4; i += 256){
            QGeo g = qgeo(i);
            const float* f = (g.s==0)?f0:((g.s==1)?f1:f2);
            float4 cf4 = *(const float4*)(conf2 + (size_t)b*TPAD + g.conf_off);
            const float* pr = f + ((size_t)b*255 + g.a*85 + 5 + c)*(size_t)g.P + g.p;
            float pv[4];
            if (!g.tail){
                float4 t = *(const float4*)pr;
                pv[0]=t.x; pv[1]=t.y; pv[2]=t.z; pv[3]=t.w;
            } else {
                pv[0] = pr[0]; pv[1] = -INFINITY; pv[2] = -INFINITY; pv[3] = -INFINITY;
            }
            const float* cfp = (const float*)&cf4;
#pragma unroll
            for (int j=0; j<4; j++){
                float st = cfp[j]*fsigf(pv[j]);
                if (st > 0.2995f && BIN_OF(st) >= gate){
                    float sc = cfp[j]*sigf(pv[j]);
                    int pos = atomicAdd(&cnt, 1);
                    if (pos < CAP){ cs[pos] = sc; ci[pos] = g.nb + 3*(g.p + j); }
                }
            }
        }
    }
    __syncthreads();
    int n = cnt; if (n > CAP) n = CAP;

    // bitonic sort: score desc, idx asc
    int S = 128; while (S < n) S <<= 1;
    for (int t=tid; t<S; t+=256){
        if (t >= n){ cs[t] = -INFINITY; ci[t] = 0x7FFFFFFF; }
    }
    __syncthreads();
    for (int k=2; k<=S; k<<=1){
        for (int j=k>>1; j>0; j>>=1){
            for (int t=tid; t<S; t+=256){
                int ixj = t ^ j;
                if (ixj > t){
                    float s1 = cs[t], s2 = cs[ixj];
                    int   i1 = ci[t], i2 = ci[ixj];
                    bool b2_first = (s2 > s1) || (s2 == s1 && i2 < i1);
                    bool b1_first = (s1 > s2) || (s1 == s2 && i1 < i2);
                    bool desc = ((t & k) == 0);
                    bool sw = desc ? b2_first : b1_first;
                    if (sw){ cs[t]=s2; cs[ixj]=s1; ci[t]=i2; ci[ixj]=i1; }
                }
            }
            __syncthreads();
        }
    }

    // load top-100 boxes; set valid bits
    if (tid < TOPK){
        float s = cs[tid];
        float y1=0.f,x1=0.f,y2=0.f,x2=0.f;
        if (s > 0.3f){
            size_t q = ((size_t)b*NBOX + ci[tid])*4;
            y1=boxes[q]; x1=boxes[q+1]; y2=boxes[q+2]; x2=boxes[q+3];
            atomicOr(&keepw[tid>>5], 1u << (tid & 31));
        }
        by1[tid]=y1; bx1[tid]=x1; by2[tid]=y2; bx2[tid]=x2;
        bar_[tid] = (y2-y1)*(x2-x1);
    }
    __syncthreads();

    // all-pairs IoU -> suppression masks (bit j of sup[i] iff j>i and iou>0.3)
    for (int p = tid; p < TOPK*TOPK; p += 256){
        int i = p / TOPK, j = p - i*TOPK;
        if (j > i){
            float q1 = fmaxf(by1[i], by1[j]);
            float q2 = fmaxf(bx1[i], bx1[j]);
            float q3 = fminf(by2[i], by2[j]);
            float q4 = fminf(bx2[i], bx2[j]);
            float inter = fmaxf(q3-q1, 0.0f)*fmaxf(q4-q2, 0.0f);
            float iou = inter/(bar_[i] + bar_[j] - inter + 1e-9f);
            if (iou > 0.3f) atomicOr(&sup[i][j>>5], 1u << (j & 31));
        }
    }
    __syncthreads();

    // serial greedy on one thread: keep &= ~sup[i] for each surviving i
    if (tid == 0){
        unsigned k0 = keepw[0], k1 = keepw[1], k2 = keepw[2], k3 = keepw[3];
        for (int i = 0; i < TOPK; i++){
            uint4 sp = *(const uint4*)sup[i];
            unsigned kw = (i < 32) ? k0 : ((i < 64) ? k1 : ((i < 96) ? k2 : k3));
            if (kw & (1u << (i & 31))){
                k0 &= ~sp.x; k1 &= ~sp.y; k2 &= ~sp.z; k3 &= ~sp.w;
            }
        }
        keepw[0]=k0; keepw[1]=k1; keepw[2]=k2; keepw[3]=k3;
    }
    __syncthreads();

    if (tid < TOPK){
        bool kept = (keepw[tid>>5] >> (tid & 31)) & 1u;
        size_t o5 = ((size_t)(bc*TOPK + tid))*5;
        out[o5+0] = kept ? by1[tid] : 0.f;
        out[o5+1] = kept ? bx1[tid] : 0.f;
        out[o5+2] = kept ? by2[tid] : 0.f;
        out[o5+3] = kept ? bx2[tid] : 0.f;
        out[o5+4] = kept ? cs[tid]  : 0.f;
    }
}

// -------- per-image top-50 cap via histogram select --------
__global__ __launch_bounds__(1024)
void cap_kernel(float* __restrict__ out)
{
    int b = blockIdx.x, tid = threadIdx.x;
    __shared__ unsigned int h[256];
    __shared__ int sufA[256], sufB[256];
    __shared__ float cs[512];
    __shared__ int   ci[512];
    __shared__ int cnt, T50;
    __shared__ unsigned char msk[NSLOT];
    if (tid < 256) h[tid] = 0;
    if (tid == 0){ cnt = 0; T50 = 0; }
    for (int u=tid; u<NSLOT; u+=1024) msk[u] = 0;
    __syncthreads();

    for (int u=tid; u<NSLOT; u+=1024){
        float v = out[((size_t)b*NSLOT + u)*5 + 4];
        if (v > 0.0f) atomicAdd(&h[BIN_OF(v)], 1u);
    }
    __syncthreads();

    if (tid < 256) sufA[tid] = (int)h[tid];
    __syncthreads();
    int* cur = sufA; int* nxt = sufB;
    for (int d=1; d<256; d<<=1){
        if (tid < 256) nxt[tid] = cur[tid] + ((tid+d) < 256 ? cur[tid+d] : 0);
        __syncthreads();
        int* t_ = cur; cur = nxt; nxt = t_;
    }
    if (tid < 256){
        if (cur[tid] >= 50 && (tid == 255 || cur[tid+1] < 50)) T50 = tid;
    }
    __syncthreads();
    int T = T50;

    for (int u=tid; u<NSLOT; u+=1024){
        float v = out[((size_t)b*NSLOT + u)*5 + 4];
        if (v > 0.0f && BIN_OF(v) >= T){
            int pos = atomicAdd(&cnt, 1);
            if (pos < 512){ cs[pos] = v; ci[pos] = u; }
        }
    }
    __syncthreads();
    int n = cnt; if (n > 512) n = 512;
    for (int t=tid; t<512; t+=1024){
        if (t >= n){ cs[t] = -INFINITY; ci[t] = 0x7FFFFFFF; }
    }
    __syncthreads();

    int S = 64; while (S < n) S <<= 1;
    for (int k=2; k<=S; k<<=1){
        for (int j=k>>1; j>0; j>>=1){
            for (int t=tid; t<S; t+=1024){
                int ixj = t ^ j;
                if (ixj > t){
                    float s1 = cs[t], s2 = cs[ixj];
                    int   i1 = ci[t], i2 = ci[ixj];
                    bool b2_first = (s2 > s1) || (s2 == s1 && i2 < i1);
                    bool b1_first = (s1 > s2) || (s1 == s2 && i1 < i2);
                    bool desc = ((t & k) == 0);
                    bool sw = desc ? b2_first : b1_first;
                    if (sw){ cs[t]=s2; cs[ixj]=s1; ci[t]=i2; ci[ixj]=i1; }
                }
            }
            __syncthreads();
        }
    }

    if (tid < 50 && tid < n) msk[ci[tid]] = 1;
    __syncthreads();

    for (int u=tid; u<NSLOT; u+=1024){
        size_t o5 = ((size_t)b*NSLOT + u)*5;
        float v = out[o5 + 4];
        if (v > 0.0f && !msk[u]){
            out[o5+0]=0.f; out[o5+1]=0.f; out[o5+2]=0.f; out[o5+3]=0.f; out[o5+4]=0.f;
        }
    }
}

extern "C" void kernel_launch(void* const* d_in, const int* in_sizes, int n_in,
                              void* d_out, int out_size, void* d_ws, size_t ws_size,
                              hipStream_t stream)
{
    const float* f0 = (const float*)d_in[0];
    const float* f1 = (const float*)d_in[1];
    const float* f2 = (const float*)d_in[2];
    const float* anchors = (const float*)d_in[3];
    const float* ishape  = (const float*)d_in[4];
    float* out = (float*)d_out;

    float* boxes = (float*)d_ws;                                   // 16*22743*4
    float* conf2 = boxes + (size_t)BATCH*NBOX*4;                   // 16*22752
    unsigned* ghist = (unsigned*)(conf2 + (size_t)BATCH*TPAD);     // 1280*256
    unsigned char* binb = (unsigned char*)(ghist + (size_t)NZERO); // 16*80*22752 B

    size_t words = (size_t)BATCH*NBOX*4 + (size_t)BATCH*TPAD + (size_t)NZERO;
    size_t need = words*4 + (size_t)BATCH*NCLS*TPAD;
    bool useB = ws_size >= need;

    dim3 dgrid((NQ4 + 255)/256, BATCH);
    decode_kernel<<<dgrid, 256, 0, stream>>>(f0, f1, f2, anchors, ishape,
                                             boxes, conf2, ghist);

    dim3 hgrid(NCLS/4, BATCH, NSEG);
    if (useB)
        scan_kernel<true><<<hgrid, 256, 0, stream>>>(f0, f1, f2, conf2, ghist, binb);
    else
        scan_kernel<false><<<hgrid, 256, 0, stream>>>(f0, f1, f2, conf2, ghist, binb);

    dim3 sgrid(NCLS, BATCH);
    if (useB)
        selnms_kernel<true><<<sgrid, 256, 0, stream>>>(f0, f1, f2, conf2, binb,
                                                       ghist, boxes, out);
    else
        selnms_kernel<false><<<sgrid, 256, 0, stream>>>(f0, f1, f2, conf2, binb,
                                                        ghist, boxes, out);

    cap_kernel<<<BATCH, 1024, 0, stream>>>(out);
}